// Round 1
// baseline (1162.400 us; speedup 1.0000x reference)
//
#include <hip/hip_runtime.h>
#include <hip/hip_bf16.h>

#define BB 256
#define DD 512
#define LL 32
#define HWN 196
#define TT 8

typedef __hip_bfloat16 bf16;
typedef __attribute__((ext_vector_type(8))) short short8;
typedef __attribute__((ext_vector_type(4))) float f32x4;

__device__ __forceinline__ float b2f(bf16 x) { return __bfloat162float(x); }
__device__ __forceinline__ bf16 f2b(float x) { return __float2bfloat16(x); }
__device__ __forceinline__ unsigned short f2bu(float x) {
    bf16 h = __float2bfloat16(x);
    return *(unsigned short*)&h;
}
#define NEG_INF (-__builtin_huge_valf())

// ---------------- f32 -> bf16 weight convert (vectorized x4) ----------------
__global__ __launch_bounds__(256) void cvt_w_kernel(
    const float* __restrict__ src, unsigned short* __restrict__ dst, int n4)
{
    int i = blockIdx.x*256 + threadIdx.x;
    if (i < n4) {
        float4 f = ((const float4*)src)[i];
        ushort4 u;
        u.x = f2bu(f.x); u.y = f2bu(f.y); u.z = f2bu(f.z); u.w = f2bu(f.w);
        ((ushort4*)dst)[i] = u;
    }
}

// ---------------- small GEMM: out[b,d] = sum_k X[b,k]*W[d,k] + bias[d] ----------------
__global__ __launch_bounds__(256) void small_gemm_kernel(
    const float* __restrict__ A1, int K1,
    const float* __restrict__ A2, int K2,
    const float* __restrict__ Wt, const float* __restrict__ bias,
    float* __restrict__ outf, int Dout)
{
    __shared__ float xs[1024];
    int b = blockIdx.x, tid = threadIdx.x;
    int K = K1 + K2;
    for (int i = tid; i < K; i += 256) {
        xs[i] = (i < K1) ? A1[(size_t)b*K1 + i] : A2[(size_t)b*K2 + (i - K1)];
    }
    __syncthreads();
    for (int d = tid; d < Dout; d += 256) {
        const float4* wrow = (const float4*)(Wt + (size_t)d * K);
        float acc = 0.f;
        for (int j = 0; j < K/4; ++j) {
            float4 w = wrow[j];
            acc += w.x*xs[j*4] + w.y*xs[j*4+1] + w.z*xs[j*4+2] + w.w*xs[j*4+3];
        }
        if (bias) acc += bias[d];
        outf[(size_t)b*Dout + d] = acc;
    }
}

// ---------------- ControlUnit attention ----------------
__global__ __launch_bounds__(256) void control_kernel(
    const float* __restrict__ cq, const float* __restrict__ cw,
    const float* __restrict__ Wca, const float* __restrict__ bca,
    const int* __restrict__ mask,
    float* __restrict__ cnew_f, float* __restrict__ cv_out, float* __restrict__ cnew_out)
{
    __shared__ float u[DD];
    __shared__ float cas[LL];
    __shared__ float cvs[LL];
    int b = blockIdx.x, tid = threadIdx.x;
    for (int d = tid; d < DD; d += 256) u[d] = cq[(size_t)b*DD + d] * Wca[d];
    __syncthreads();
    int wave = tid >> 6, lane = tid & 63;
    float bca0 = bca[0];
    for (int lw = 0; lw < 8; ++lw) {
        int l = wave*8 + lw;
        const float4* w4 = (const float4*)(cw + ((size_t)(b*LL + l))*DD + lane*8);
        float4 wa = w4[0], wb = w4[1];
        const float* uu = &u[lane*8];
        float p = wa.x*uu[0] + wa.y*uu[1] + wa.z*uu[2] + wa.w*uu[3]
                + wb.x*uu[4] + wb.y*uu[5] + wb.z*uu[6] + wb.w*uu[7];
        for (int off = 32; off > 0; off >>= 1) p += __shfl_down(p, off);
        if (lane == 0) {
            float v = p + bca0;
            if (mask[b*LL + l] <= 0) v = NEG_INF;
            cas[l] = v;
        }
    }
    __syncthreads();
    if (tid < LL) {
        float mx = NEG_INF;
        for (int j = 0; j < LL; ++j) mx = fmaxf(mx, cas[j]);
        float s = 0.f;
        for (int j = 0; j < LL; ++j) s += __expf(cas[j] - mx);
        float cv = __expf(cas[tid] - mx) / s;
        cvs[tid] = cv;
        cv_out[b*LL + tid] = cv;
    }
    __syncthreads();
    for (int d = tid; d < DD; d += 256) {
        float acc = 0.f;
        for (int l = 0; l < LL; ++l) acc += cvs[l] * cw[((size_t)(b*LL + l))*DD + d];
        cnew_f[(size_t)b*DD + d] = acc;
        cnew_out[(size_t)b*DD + d] = acc;
    }
}

// cell of 4 channel-rows x 4 hw cols; raw f32 or bf16 bits held in regs
typedef union { float4 f4[4]; ushort4 u4[4]; } LCell;

// ---------------- MFMA conv1x1 batched GEMM ----------------
// Y[b,o,hw] = (sum_c W[o,c]*X[c,hw] + bias[o]) * (oscale ? oscale[b,o] : 1)
// X = concat_c(X1[b,C1,hw], X2[b,C-C1,hw]); each source f32 or bf16.
// Block: 256 thr = 4 waves; wave (wm,wn): 4 m-tiles x 7/6 n-tiles of 16x16x32 MFMA.
// Grid: (256 b, 4 ot)  -> linear id = ot*256+b -> all 4 ot-blocks of one b land on
// XCD b%8 and share the X[b] L2 fill (was (4,256): 4 different XCDs, ~2x overfetch).
// K-loop is double-buffered: next tile is loaded to regs under current tile's MFMAs
// (async-stage split), one __syncthreads per step.
__global__ __launch_bounds__(256) void conv_mfma_kernel(
    const void* __restrict__ X1, int x1f32, int C1,
    const void* __restrict__ X2, int x2f32,
    const unsigned short* __restrict__ Wb, int C,
    const float* __restrict__ bias, const float* __restrict__ oscale,
    unsigned short* __restrict__ Y)
{
    // Xs[buf][kq*212 + n]: kq = (k within 32-step)/4, cell = 4 bf16 along k.
    __shared__ __align__(16) uint2 Xs[2][8*212];
    int b = blockIdx.x, ot = blockIdx.y;
    int tid = threadIdx.x;
    int wave = tid >> 6, lane = tid & 63;
    int wm = wave >> 1, wn = wave & 1;
    int obase = ot*128 + wm*64;
    int n0 = wn*112;              // wn0: tiles 0..6 (n 0..111), wn1: tiles 0..5 (n 112..207)
    int ntn = wn ? 6 : 7;
    int ln = lane & 15, lq = lane >> 4;
    int C2 = C - C1;

    // staging cell assignment (8*49 = 392 cells over 256 threads)
    int idx1 = tid + 256;
    int n4_0 = tid % 49,  kq_0 = tid / 49;
    int n4_1 = idx1 % 49, kq_1 = idx1 / 49;
    bool v1 = idx1 < 8*49;

    LCell preA, preB;

    auto LOADC = [&](LCell& pc, int c0, int kq, int n4) {
        int c = c0 + kq*4;
        if (c < C1) {
            if (x1f32) {
                const float* p = (const float*)X1 + ((size_t)b*C1 + c)*HWN + n4*4;
                #pragma unroll
                for (int i = 0; i < 4; ++i) pc.f4[i] = *(const float4*)(p + (size_t)i*HWN);
            } else {
                const unsigned short* p = (const unsigned short*)X1 + ((size_t)b*C1 + c)*HWN + n4*4;
                #pragma unroll
                for (int i = 0; i < 4; ++i) pc.u4[i] = *(const ushort4*)(p + (size_t)i*HWN);
            }
        } else {
            if (x2f32) {
                const float* p = (const float*)X2 + ((size_t)b*C2 + (c - C1))*HWN + n4*4;
                #pragma unroll
                for (int i = 0; i < 4; ++i) pc.f4[i] = *(const float4*)(p + (size_t)i*HWN);
            } else {
                const unsigned short* p = (const unsigned short*)X2 + ((size_t)b*C2 + (c - C1))*HWN + n4*4;
                #pragma unroll
                for (int i = 0; i < 4; ++i) pc.u4[i] = *(const ushort4*)(p + (size_t)i*HWN);
            }
        }
    };
    auto PACKC = [&](LCell& pc, int c0, int kq, int n4, int buf) {
        int c = c0 + kq*4;
        int isf = (c < C1) ? x1f32 : x2f32;
        ushort4 r[4];
        if (isf) {
            #pragma unroll
            for (int i = 0; i < 4; ++i) {
                float4 f = pc.f4[i];
                r[i].x = f2bu(f.x); r[i].y = f2bu(f.y); r[i].z = f2bu(f.z); r[i].w = f2bu(f.w);
            }
        } else {
            #pragma unroll
            for (int i = 0; i < 4; ++i) r[i] = pc.u4[i];
        }
        uint2* cell = &Xs[buf][kq*212 + n4*4];
        *(uint4*)(cell) = make_uint4(
            (uint)r[0].x | ((uint)r[1].x << 16), (uint)r[2].x | ((uint)r[3].x << 16),
            (uint)r[0].y | ((uint)r[1].y << 16), (uint)r[2].y | ((uint)r[3].y << 16));
        *(uint4*)(cell + 2) = make_uint4(
            (uint)r[0].z | ((uint)r[1].z << 16), (uint)r[2].z | ((uint)r[3].z << 16),
            (uint)r[0].w | ((uint)r[1].w << 16), (uint)r[2].w | ((uint)r[3].w << 16));
    };

    f32x4 acc[4][7];
    #pragma unroll
    for (int mt = 0; mt < 4; ++mt)
        #pragma unroll
        for (int nt = 0; nt < 7; ++nt) acc[mt][nt] = (f32x4){0.f, 0.f, 0.f, 0.f};

    // A-fragment double buffer (weights, L2-resident). Issued BEFORE X prefetch so
    // the MFMA's waitcnt for them never drains the X loads.
    short8 a_cur[4], a_nxt[4];
    #pragma unroll
    for (int mt = 0; mt < 4; ++mt)
        a_cur[mt] = *(const short8*)(Wb + (size_t)(obase + mt*16 + ln)*C + 0 + lq*8);

    // prologue: stage tile 0
    LOADC(preA, 0, kq_0, n4_0);
    if (v1) LOADC(preB, 0, kq_1, n4_1);
    PACKC(preA, 0, kq_0, n4_0, 0);
    if (v1) PACKC(preB, 0, kq_1, n4_1, 0);
    __syncthreads();

    int nsteps = C/32;
    for (int s = 0; s < nsteps; ++s) {
        int buf = s & 1;
        int c0 = s*32;
        bool more = (s + 1 < nsteps);
        if (more) {
            #pragma unroll
            for (int mt = 0; mt < 4; ++mt)
                a_nxt[mt] = *(const short8*)(Wb + (size_t)(obase + mt*16 + ln)*C + (c0+32) + lq*8);
            LOADC(preA, c0+32, kq_0, n4_0);
            if (v1) LOADC(preB, c0+32, kq_1, n4_1);
        }
        // ---- MFMA over n-tiles on current buffer ----
        #pragma unroll
        for (int nt = 0; nt < 7; ++nt) {
            if (nt < ntn) {
                int n = n0 + nt*16 + ln;
                uint2 b0 = Xs[buf][(lq*2)*212 + n];
                uint2 b1 = Xs[buf][(lq*2 + 1)*212 + n];
                union { uint4 u; short8 s8; } bb;
                bb.u = make_uint4(b0.x, b0.y, b1.x, b1.y);
                #pragma unroll
                for (int mt = 0; mt < 4; ++mt)
                    acc[mt][nt] = __builtin_amdgcn_mfma_f32_16x16x32_bf16(a_cur[mt], bb.s8, acc[mt][nt], 0, 0, 0);
            }
        }
        if (more) {
            PACKC(preA, c0+32, kq_0, n4_0, buf^1);
            if (v1) PACKC(preB, c0+32, kq_1, n4_1, buf^1);
            #pragma unroll
            for (int mt = 0; mt < 4; ++mt) a_cur[mt] = a_nxt[mt];
        }
        __syncthreads();
    }

    // ---- epilogue: C/D layout col = lane&15, row = (lane>>4)*4 + reg ----
    #pragma unroll
    for (int mt = 0; mt < 4; ++mt) {
        #pragma unroll
        for (int rr = 0; rr < 4; ++rr) {
            int o = obase + mt*16 + lq*4 + rr;
            float bo = bias[o];
            float os = oscale ? oscale[(size_t)b*DD + o] : 1.f;
            #pragma unroll
            for (int nt = 0; nt < 7; ++nt) {
                int hw = n0 + nt*16 + ln;
                if (hw < HWN) {
                    float v = (acc[mt][nt][rr] + bo) * os;
                    Y[((size_t)b*DD + o)*HWN + hw] = f2bu(v);
                }
            }
        }
    }
}

// ---------------- channel softmax (512 c per (b,hw)) + r[b,c] = sum_hw rv*k ----------------
__global__ __launch_bounds__(512) void softmax_r_kernel(
    const bf16* __restrict__ ra, const float* __restrict__ kin,
    float* __restrict__ rv, float* __restrict__ r)
{
    __shared__ float pm[2][HWN], ps[2][HWN];
    __shared__ float mxs[HWN], sis[HWN];
    int b = blockIdx.x, tid = threadIdx.x;
    int half = tid >> 8, hw = tid & 255;
    if (hw < HWN) {
        float m = NEG_INF, s = 0.f;
        const bf16* base = ra + ((size_t)b*DD + half*256)*HWN + hw;
        for (int c = 0; c < 256; ++c) {
            float x = b2f(base[(size_t)c*HWN]);
            float nm = fmaxf(m, x);
            s = s*__expf(m - nm) + __expf(x - nm);
            m = nm;
        }
        pm[half][hw] = m; ps[half][hw] = s;
    }
    __syncthreads();
    if (tid < HWN) {
        float m0 = pm[0][tid], m1 = pm[1][tid];
        float m = fmaxf(m0, m1);
        float s = ps[0][tid]*__expf(m0 - m) + ps[1][tid]*__expf(m1 - m);
        mxs[tid] = m; sis[tid] = 1.f/s;
    }
    __syncthreads();
    int wave = tid >> 6, lane = tid & 63;
    for (int ci = 0; ci < 64; ++ci) {
        int c = wave*64 + ci;
        float psum = 0.f;
        #pragma unroll
        for (int g = 0; g < 4; ++g) {
            int hw2 = lane + 64*g;
            if (hw2 < HWN) {
                size_t idx = ((size_t)b*DD + c)*HWN + hw2;
                float e = __expf(b2f(ra[idx]) - mxs[hw2]) * sis[hw2];
                rv[idx] = e;
                psum += e * kin[idx];
            }
        }
        for (int off = 32; off > 0; off >>= 1) psum += __shfl_down(psum, off);
        if (lane == 0) r[(size_t)b*DD + c] = psum;
    }
}

// ---------------- sa softmax over T and m_sa (gate fused in) ----------------
__global__ __launch_bounds__(256) void samsa_kernel(
    const float* __restrict__ cs, const float* __restrict__ ms,
    const float* __restrict__ Wsa, const float* __restrict__ bsa,
    const float* __restrict__ cnew, const float* __restrict__ Wc, const float* __restrict__ bc,
    float* __restrict__ gate_out, float* __restrict__ msa)
{
    __shared__ float lg[TT];
    __shared__ float sas[TT];
    __shared__ float xw[DD];
    __shared__ float gsh;
    int b = blockIdx.x, tid = threadIdx.x;
    int wave = tid >> 6, lane = tid & 63;
    for (int d = tid; d < DD; d += 256) xw[d] = Wsa[d];
    __syncthreads();
    for (int tw = 0; tw < 2; ++tw) {
        int t = wave + 4*tw;
        const float4* c4 = (const float4*)(cs + ((size_t)t*BB + b)*DD + lane*8);
        float4 ca = c4[0], cb = c4[1];
        const float* ww = &xw[lane*8];
        float p = ca.x*ww[0] + ca.y*ww[1] + ca.z*ww[2] + ca.w*ww[3]
                + cb.x*ww[4] + cb.y*ww[5] + cb.z*ww[6] + cb.w*ww[7];
        for (int off = 32; off > 0; off >>= 1) p += __shfl_down(p, off);
        if (lane == 0) lg[t] = p;           // raw dot; gate applied after
    }
    if (wave == 0) {
        const float4* w4 = (const float4*)(Wc + lane*8);
        const float* x = &cnew[(size_t)b*DD + lane*8];
        float4 wa = w4[0], wb = w4[1];
        float p = wa.x*x[0] + wa.y*x[1] + wa.z*x[2] + wa.w*x[3]
                + wb.x*x[4] + wb.y*x[5] + wb.z*x[6] + wb.w*x[7];
        for (int off = 32; off > 0; off >>= 1) p += __shfl_down(p, off);
        if (lane == 0) {
            float g = 1.f / (1.f + __expf(-(p + bc[0])));
            gsh = g; gate_out[b] = g;
        }
    }
    __syncthreads();
    if (tid < TT) {
        float g = gsh, b0 = bsa[0];
        float mx = NEG_INF;
        for (int j = 0; j < TT; ++j) mx = fmaxf(mx, g*lg[j] + b0);
        float s = 0.f;
        for (int j = 0; j < TT; ++j) s += __expf(g*lg[j] + b0 - mx);
        sas[tid] = __expf(g*lg[tid] + b0 - mx) / s;
    }
    __syncthreads();
    for (int d = tid; d < DD; d += 256) {
        float acc = 0.f;
        for (int t = 0; t < TT; ++t) acc += sas[t] * ms[((size_t)t*BB + b)*DD + d];
        msa[(size_t)b*DD + d] = acc;
    }
}

// ---------------- m_new = g*m + (1-g)*(mund + msa@Ws^T)  (GEMM + final fused) ----------------
__global__ __launch_bounds__(256) void write_final_kernel(
    const float* __restrict__ msa, const float* __restrict__ Ws,
    const float* __restrict__ m, const float* __restrict__ gate,
    const float* __restrict__ mund, float* __restrict__ mnew)
{
    __shared__ float xs[DD];
    int b = blockIdx.x, tid = threadIdx.x;
    for (int i = tid; i < DD; i += 256) xs[i] = msa[(size_t)b*DD + i];
    __syncthreads();
    float g = gate[b];
    for (int d = tid; d < DD; d += 256) {
        const float4* wrow = (const float4*)(Ws + (size_t)d * DD);
        float acc = 0.f;
        for (int j = 0; j < DD/4; ++j) {
            float4 w = wrow[j];
            acc += w.x*xs[j*4] + w.y*xs[j*4+1] + w.z*xs[j*4+2] + w.w*xs[j*4+3];
        }
        size_t idx = (size_t)b*DD + d;
        mnew[idx] = g * m[idx] + (1.f - g) * (mund[idx] + acc);
    }
}

extern "C" void kernel_launch(void* const* d_in, const int* in_sizes, int n_in,
                              void* d_out, int out_size, void* d_ws, size_t ws_size,
                              hipStream_t stream)
{
    (void)in_sizes; (void)n_in; (void)out_size; (void)ws_size;
    const float* c    = (const float*)d_in[0];
    const float* m    = (const float*)d_in[1];
    const float* k    = (const float*)d_in[2];
    const float* q    = (const float*)d_in[3];
    const float* cw   = (const float*)d_in[4];
    const int*   mask = (const int*)  d_in[5];
    const float* cs   = (const float*)d_in[6];
    const float* ms   = (const float*)d_in[7];
    const float* Wcq  = (const float*)d_in[8];
    const float* bcq  = (const float*)d_in[9];
    const float* Wca  = (const float*)d_in[10];
    const float* bca  = (const float*)d_in[11];
    const float* Wm_r = (const float*)d_in[12];
    const float* bm_r = (const float*)d_in[13];
    const float* Wk   = (const float*)d_in[14];
    const float* bk   = (const float*)d_in[15];
    const float* WI   = (const float*)d_in[16];
    const float* bI   = (const float*)d_in[17];
    const float* Wra  = (const float*)d_in[18];
    const float* bra  = (const float*)d_in[19];
    const float* Wm_w = (const float*)d_in[20];
    const float* bm_w = (const float*)d_in[21];
    const float* Wsa  = (const float*)d_in[22];
    const float* bsa  = (const float*)d_in[23];
    const float* Wm2  = (const float*)d_in[24];
    const float* bm2  = (const float*)d_in[25];
    const float* Wc   = (const float*)d_in[26];
    const float* bc   = (const float*)d_in[27];
    const float* Ws   = (const float*)d_in[28];

    float* out_cnew = (float*)d_out;
    float* out_mnew = out_cnew + BB*DD;
    float* out_cv   = out_mnew + BB*DD;
    float* out_rv   = out_cv + BB*LL;     // 25,690,112 f32 = 102,760,448 B

    // d_out rv region doubles as bf16 scratch for I / I2' (both dead before rv is written)
    unsigned short* I_w  = (unsigned short*)out_rv;                       // 51,380,224 B
    unsigned short* I2_w = (unsigned short*)((char*)out_rv + 51380224);   // 51,380,224 B

    char* w = (char*)d_ws;                 // total footprint: 55,575,552 B
    float* s0      = (float*)(w + 0);        // cq -> r
    float* s1      = (float*)(w + 524288);   // cnew
    float* s2      = (float*)(w + 1048576);  // mI -> mund
    float* s3      = (float*)(w + 1572864);  // mprev -> msa
    unsigned short* Wkb  = (unsigned short*)(w + 2097152);   // 512x512 bf16
    unsigned short* WIb  = (unsigned short*)(w + 2621440);   // 512x1024 bf16
    unsigned short* Wrab = (unsigned short*)(w + 3670016);   // 512x512 bf16
    unsigned short* ra_w = (unsigned short*)(w + 4194304);   // [B,D,HW] bf16, 51,380,224 B
    float* gate_w  = (float*)(w + 55574528); // 1024 B

    float* cq_w   = s0;
    float* r_w    = s0;
    float* cnew_w = s1;
    float* mI_w   = s2;
    float* mund_w = s2;
    float* mprev_w= s3;
    float* msa_w  = s3;

    // Weight converts (f32 -> bf16), L2-resident thereafter
    cvt_w_kernel<<<256, 256, 0, stream>>>(Wk,  Wkb,  65536);
    cvt_w_kernel<<<512, 256, 0, stream>>>(WI,  WIb,  131072);
    cvt_w_kernel<<<256, 256, 0, stream>>>(Wra, Wrab, 65536);

    // ControlUnit
    small_gemm_kernel<<<BB, 256, 0, stream>>>(c, DD, q, DD, Wcq, bcq, cq_w, DD);
    small_gemm_kernel<<<BB, 256, 0, stream>>>(m, DD, nullptr, 0, Wm_r, bm_r, mI_w, DD);
    control_kernel<<<BB, 256, 0, stream>>>(cq_w, cw, Wca, bca, mask, cnew_w, out_cv, out_cnew);

    // ReadUnit (MFMA convs): I = mI.(Wk k + bk); I2' = (WI [I;k] + bI).cnew; ra = Wra I2' + bra
    conv_mfma_kernel<<<dim3(BB, 4), 256, 0, stream>>>(k,    1, DD, nullptr, 0, Wkb,  DD,   bk,  mI_w,   I_w);
    conv_mfma_kernel<<<dim3(BB, 4), 256, 0, stream>>>(I_w,  0, DD, k,       1, WIb,  2*DD, bI,  cnew_w, I2_w);
    conv_mfma_kernel<<<dim3(BB, 4), 256, 0, stream>>>(I2_w, 0, DD, nullptr, 0, Wrab, DD,   bra, nullptr, ra_w);
    softmax_r_kernel<<<BB, 512, 0, stream>>>((const bf16*)ra_w, k, out_rv, r_w);

    // WriteUnit
    small_gemm_kernel<<<BB, 256, 0, stream>>>(r_w, DD, m, DD, Wm_w, bm_w, mprev_w, DD);
    small_gemm_kernel<<<BB, 256, 0, stream>>>(mprev_w, DD, nullptr, 0, Wm2, bm2, mund_w, DD);
    samsa_kernel<<<BB, 256, 0, stream>>>(cs, ms, Wsa, bsa, cnew_w, Wc, bc, gate_w, msa_w);
    write_final_kernel<<<BB, 256, 0, stream>>>(msa_w, Ws, m, gate_w, mund_w, out_mnew);
}

// Round 2
// 776.096 us; speedup vs baseline: 1.4978x; 1.4978x over previous
//
#include <hip/hip_runtime.h>
#include <hip/hip_bf16.h>

#define BB 256
#define DD 512
#define LL 32
#define HWN 196
#define TT 8

typedef __hip_bfloat16 bf16;
typedef __attribute__((ext_vector_type(8))) short short8;
typedef __attribute__((ext_vector_type(4))) float f32x4;

__device__ __forceinline__ float b2f(bf16 x) { return __bfloat162float(x); }
__device__ __forceinline__ bf16 f2b(float x) { return __float2bfloat16(x); }
__device__ __forceinline__ unsigned short f2bu(float x) {
    bf16 h = __float2bfloat16(x);
    return *(unsigned short*)&h;
}
#define NEG_INF (-__builtin_huge_valf())

// ---------------- f32 -> bf16 weight convert (vectorized x4) ----------------
__global__ __launch_bounds__(256) void cvt_w_kernel(
    const float* __restrict__ src, unsigned short* __restrict__ dst, int n4)
{
    int i = blockIdx.x*256 + threadIdx.x;
    if (i < n4) {
        float4 f = ((const float4*)src)[i];
        ushort4 u;
        u.x = f2bu(f.x); u.y = f2bu(f.y); u.z = f2bu(f.z); u.w = f2bu(f.w);
        ((ushort4*)dst)[i] = u;
    }
}

// ---------------- small GEMM: out[b,d] = sum_k X[b,k]*W[d,k] + bias[d] ----------------
__global__ __launch_bounds__(256) void small_gemm_kernel(
    const float* __restrict__ A1, int K1,
    const float* __restrict__ A2, int K2,
    const float* __restrict__ Wt, const float* __restrict__ bias,
    float* __restrict__ outf, int Dout)
{
    __shared__ float xs[1024];
    int b = blockIdx.x, tid = threadIdx.x;
    int K = K1 + K2;
    for (int i = tid; i < K; i += 256) {
        xs[i] = (i < K1) ? A1[(size_t)b*K1 + i] : A2[(size_t)b*K2 + (i - K1)];
    }
    __syncthreads();
    for (int d = tid; d < Dout; d += 256) {
        const float4* wrow = (const float4*)(Wt + (size_t)d * K);
        float acc = 0.f;
        for (int j = 0; j < K/4; ++j) {
            float4 w = wrow[j];
            acc += w.x*xs[j*4] + w.y*xs[j*4+1] + w.z*xs[j*4+2] + w.w*xs[j*4+3];
        }
        if (bias) acc += bias[d];
        outf[(size_t)b*Dout + d] = acc;
    }
}

// ---------------- ControlUnit attention ----------------
__global__ __launch_bounds__(256) void control_kernel(
    const float* __restrict__ cq, const float* __restrict__ cw,
    const float* __restrict__ Wca, const float* __restrict__ bca,
    const int* __restrict__ mask,
    float* __restrict__ cnew_f, float* __restrict__ cv_out, float* __restrict__ cnew_out)
{
    __shared__ float u[DD];
    __shared__ float cas[LL];
    __shared__ float cvs[LL];
    int b = blockIdx.x, tid = threadIdx.x;
    for (int d = tid; d < DD; d += 256) u[d] = cq[(size_t)b*DD + d] * Wca[d];
    __syncthreads();
    int wave = tid >> 6, lane = tid & 63;
    float bca0 = bca[0];
    for (int lw = 0; lw < 8; ++lw) {
        int l = wave*8 + lw;
        const float4* w4 = (const float4*)(cw + ((size_t)(b*LL + l))*DD + lane*8);
        float4 wa = w4[0], wb = w4[1];
        const float* uu = &u[lane*8];
        float p = wa.x*uu[0] + wa.y*uu[1] + wa.z*uu[2] + wa.w*uu[3]
                + wb.x*uu[4] + wb.y*uu[5] + wb.z*uu[6] + wb.w*uu[7];
        for (int off = 32; off > 0; off >>= 1) p += __shfl_down(p, off);
        if (lane == 0) {
            float v = p + bca0;
            if (mask[b*LL + l] <= 0) v = NEG_INF;
            cas[l] = v;
        }
    }
    __syncthreads();
    if (tid < LL) {
        float mx = NEG_INF;
        for (int j = 0; j < LL; ++j) mx = fmaxf(mx, cas[j]);
        float s = 0.f;
        for (int j = 0; j < LL; ++j) s += __expf(cas[j] - mx);
        float cv = __expf(cas[tid] - mx) / s;
        cvs[tid] = cv;
        cv_out[b*LL + tid] = cv;
    }
    __syncthreads();
    for (int d = tid; d < DD; d += 256) {
        float acc = 0.f;
        for (int l = 0; l < LL; ++l) acc += cvs[l] * cw[((size_t)(b*LL + l))*DD + d];
        cnew_f[(size_t)b*DD + d] = acc;
        cnew_out[(size_t)b*DD + d] = acc;
    }
}

// ---------------- load 4 consecutive channel-rows x 4 hw cols, as bf16 bits ----------------
__device__ __forceinline__ void load4rows(const void* X, int isf32, size_t row, int n4, ushort4 r[4]) {
    if (isf32) {
        const float* p = (const float*)X + row*HWN + n4*4;
        #pragma unroll
        for (int i = 0; i < 4; ++i) {
            float4 f = *(const float4*)(p + (size_t)i*HWN);
            r[i].x = f2bu(f.x); r[i].y = f2bu(f.y); r[i].z = f2bu(f.z); r[i].w = f2bu(f.w);
        }
    } else {
        const unsigned short* p = (const unsigned short*)X + row*HWN + n4*4;
        #pragma unroll
        for (int i = 0; i < 4; ++i) r[i] = *(const ushort4*)(p + (size_t)i*HWN);
    }
}

// ---------------- MFMA conv1x1 batched GEMM ----------------
// Y[b,o,hw] = (sum_c W[o,c]*X[c,hw] + bias[o]) * (oscale ? oscale[b,o] : 1)
// X = concat_c(X1[b,C1,hw], X2[b,C-C1,hw]); each source f32 or bf16.
// Block: 512 thr = 8 waves as 4wm x 2wn; wave = 2 m-tiles x 7/6 n-tiles of 16x16x32.
// Per-thread regs: acc 2x7x4 = 56 f32 (vs 112 in the 4-wave version) -> ~100 total
// -> 4 waves/SIMD allowed -> 2 blocks/CU resident (16 waves/CU). The kernel is
// latency-bound (MfmaUtil 15%, HBM 27%, VALU 19% all low) so TLP is the lever;
// round-1's double-buffer crossed the 256-reg boundary and halved occupancy (FAILED).
// Single-buffered LDS, 2-sync loop: second resident block covers the barrier drain.
__global__ __launch_bounds__(512) void conv_mfma_kernel(
    const void* __restrict__ X1, int x1f32, int C1,
    const void* __restrict__ X2, int x2f32,
    const unsigned short* __restrict__ Wb, int C,
    const float* __restrict__ bias, const float* __restrict__ oscale,
    unsigned short* __restrict__ Y)
{
    // Xs[kq][n]: kq = (k within 32-step)/4, cell = 4 bf16 along k. stride 212 uint2.
    __shared__ __align__(16) uint2 Xs[8*212];
    int b = blockIdx.x, ot = blockIdx.y;
    int tid = threadIdx.x;
    int wave = tid >> 6, lane = tid & 63;
    int wm = wave >> 1, wn = wave & 1;
    int obase = ot*128 + wm*32;
    int n0 = wn*112;              // wn0: tiles 0..6 (n 0..111), wn1: tiles 0..5 (n 112..207)
    int ntn = wn ? 6 : 7;
    int ln = lane & 15, lq = lane >> 4;
    int C2 = C - C1;

    // staging cell assignment (8*49 = 392 cells, threads 392..511 idle in staging)
    int n4_0 = tid % 49, kq_0 = tid / 49;
    bool st = tid < 8*49;

    f32x4 acc[2][7];
    #pragma unroll
    for (int mt = 0; mt < 2; ++mt)
        #pragma unroll
        for (int nt = 0; nt < 7; ++nt) acc[mt][nt] = (f32x4){0.f, 0.f, 0.f, 0.f};

    for (int c0 = 0; c0 < C; c0 += 32) {
        __syncthreads();
        // ---- stage + transpose X tile: [32 k x 196 n] -> Xs[kq][n] (k-quads packed) ----
        if (st) {
            int c = c0 + kq_0*4;
            ushort4 r[4];
            if (c < C1) load4rows(X1, x1f32, (size_t)b*C1 + c, n4_0, r);
            else        load4rows(X2, x2f32, (size_t)b*C2 + (c - C1), n4_0, r);
            uint2* cell = &Xs[kq_0*212 + n4_0*4];
            *(uint4*)(cell) = make_uint4(
                (uint)r[0].x | ((uint)r[1].x << 16), (uint)r[2].x | ((uint)r[3].x << 16),
                (uint)r[0].y | ((uint)r[1].y << 16), (uint)r[2].y | ((uint)r[3].y << 16));
            *(uint4*)(cell + 2) = make_uint4(
                (uint)r[0].z | ((uint)r[1].z << 16), (uint)r[2].z | ((uint)r[3].z << 16),
                (uint)r[0].w | ((uint)r[1].w << 16), (uint)r[2].w | ((uint)r[3].w << 16));
        }
        __syncthreads();
        // ---- A-fragments straight from global (bf16 weights, L2-resident) ----
        short8 a[2];
        #pragma unroll
        for (int mt = 0; mt < 2; ++mt)
            a[mt] = *(const short8*)(Wb + (size_t)(obase + mt*16 + ln)*C + c0 + lq*8);
        // ---- MFMA over n-tiles ----
        #pragma unroll
        for (int nt = 0; nt < 7; ++nt) {
            if (nt < ntn) {
                int n = n0 + nt*16 + ln;
                uint2 b0 = Xs[(lq*2)*212 + n];
                uint2 b1 = Xs[(lq*2 + 1)*212 + n];
                union { uint4 u; short8 s8; } bb;
                bb.u = make_uint4(b0.x, b0.y, b1.x, b1.y);
                #pragma unroll
                for (int mt = 0; mt < 2; ++mt)
                    acc[mt][nt] = __builtin_amdgcn_mfma_f32_16x16x32_bf16(a[mt], bb.s8, acc[mt][nt], 0, 0, 0);
            }
        }
    }
    // ---- epilogue: C/D layout col = lane&15, row = (lane>>4)*4 + reg ----
    #pragma unroll
    for (int mt = 0; mt < 2; ++mt) {
        #pragma unroll
        for (int rr = 0; rr < 4; ++rr) {
            int o = obase + mt*16 + lq*4 + rr;
            float bo = bias[o];
            float os = oscale ? oscale[(size_t)b*DD + o] : 1.f;
            #pragma unroll
            for (int nt = 0; nt < 7; ++nt) {
                int hw = n0 + nt*16 + ln;
                if (nt < ntn && hw < HWN) {
                    float v = (acc[mt][nt][rr] + bo) * os;
                    Y[((size_t)b*DD + o)*HWN + hw] = f2bu(v);
                }
            }
        }
    }
}

// ---------------- channel softmax (512 c per (b,hw)) + r[b,c] = sum_hw rv*k ----------------
__global__ __launch_bounds__(512) void softmax_r_kernel(
    const bf16* __restrict__ ra, const float* __restrict__ kin,
    float* __restrict__ rv, float* __restrict__ r)
{
    __shared__ float pm[2][HWN], ps[2][HWN];
    __shared__ float mxs[HWN], sis[HWN];
    int b = blockIdx.x, tid = threadIdx.x;
    int half = tid >> 8, hw = tid & 255;
    if (hw < HWN) {
        float m = NEG_INF, s = 0.f;
        const bf16* base = ra + ((size_t)b*DD + half*256)*HWN + hw;
        for (int c = 0; c < 256; ++c) {
            float x = b2f(base[(size_t)c*HWN]);
            float nm = fmaxf(m, x);
            s = s*__expf(m - nm) + __expf(x - nm);
            m = nm;
        }
        pm[half][hw] = m; ps[half][hw] = s;
    }
    __syncthreads();
    if (tid < HWN) {
        float m0 = pm[0][tid], m1 = pm[1][tid];
        float m = fmaxf(m0, m1);
        float s = ps[0][tid]*__expf(m0 - m) + ps[1][tid]*__expf(m1 - m);
        mxs[tid] = m; sis[tid] = 1.f/s;
    }
    __syncthreads();
    int wave = tid >> 6, lane = tid & 63;
    for (int ci = 0; ci < 64; ++ci) {
        int c = wave*64 + ci;
        float psum = 0.f;
        #pragma unroll
        for (int g = 0; g < 4; ++g) {
            int hw2 = lane + 64*g;
            if (hw2 < HWN) {
                size_t idx = ((size_t)b*DD + c)*HWN + hw2;
                float e = __expf(b2f(ra[idx]) - mxs[hw2]) * sis[hw2];
                rv[idx] = e;
                psum += e * kin[idx];
            }
        }
        for (int off = 32; off > 0; off >>= 1) psum += __shfl_down(psum, off);
        if (lane == 0) r[(size_t)b*DD + c] = psum;
    }
}

// ---------------- sa softmax over T and m_sa (gate fused in) ----------------
__global__ __launch_bounds__(256) void samsa_kernel(
    const float* __restrict__ cs, const float* __restrict__ ms,
    const float* __restrict__ Wsa, const float* __restrict__ bsa,
    const float* __restrict__ cnew, const float* __restrict__ Wc, const float* __restrict__ bc,
    float* __restrict__ gate_out, float* __restrict__ msa)
{
    __shared__ float lg[TT];
    __shared__ float sas[TT];
    __shared__ float xw[DD];
    __shared__ float gsh;
    int b = blockIdx.x, tid = threadIdx.x;
    int wave = tid >> 6, lane = tid & 63;
    for (int d = tid; d < DD; d += 256) xw[d] = Wsa[d];
    __syncthreads();
    for (int tw = 0; tw < 2; ++tw) {
        int t = wave + 4*tw;
        const float4* c4 = (const float4*)(cs + ((size_t)t*BB + b)*DD + lane*8);
        float4 ca = c4[0], cb = c4[1];
        const float* ww = &xw[lane*8];
        float p = ca.x*ww[0] + ca.y*ww[1] + ca.z*ww[2] + ca.w*ww[3]
                + cb.x*ww[4] + cb.y*ww[5] + cb.z*ww[6] + cb.w*ww[7];
        for (int off = 32; off > 0; off >>= 1) p += __shfl_down(p, off);
        if (lane == 0) lg[t] = p;           // raw dot; gate applied after
    }
    if (wave == 0) {
        const float4* w4 = (const float4*)(Wc + lane*8);
        const float* x = &cnew[(size_t)b*DD + lane*8];
        float4 wa = w4[0], wb = w4[1];
        float p = wa.x*x[0] + wa.y*x[1] + wa.z*x[2] + wa.w*x[3]
                + wb.x*x[4] + wb.y*x[5] + wb.z*x[6] + wb.w*x[7];
        for (int off = 32; off > 0; off >>= 1) p += __shfl_down(p, off);
        if (lane == 0) {
            float g = 1.f / (1.f + __expf(-(p + bc[0])));
            gsh = g; gate_out[b] = g;
        }
    }
    __syncthreads();
    if (tid < TT) {
        float g = gsh, b0 = bsa[0];
        float mx = NEG_INF;
        for (int j = 0; j < TT; ++j) mx = fmaxf(mx, g*lg[j] + b0);
        float s = 0.f;
        for (int j = 0; j < TT; ++j) s += __expf(g*lg[j] + b0 - mx);
        sas[tid] = __expf(g*lg[tid] + b0 - mx) / s;
    }
    __syncthreads();
    for (int d = tid; d < DD; d += 256) {
        float acc = 0.f;
        for (int t = 0; t < TT; ++t) acc += sas[t] * ms[((size_t)t*BB + b)*DD + d];
        msa[(size_t)b*DD + d] = acc;
    }
}

// ---------------- m_new = g*m + (1-g)*(mund + msa@Ws^T)  (GEMM + final fused) ----------------
__global__ __launch_bounds__(256) void write_final_kernel(
    const float* __restrict__ msa, const float* __restrict__ Ws,
    const float* __restrict__ m, const float* __restrict__ gate,
    const float* __restrict__ mund, float* __restrict__ mnew)
{
    __shared__ float xs[DD];
    int b = blockIdx.x, tid = threadIdx.x;
    for (int i = tid; i < DD; i += 256) xs[i] = msa[(size_t)b*DD + i];
    __syncthreads();
    float g = gate[b];
    for (int d = tid; d < DD; d += 256) {
        const float4* wrow = (const float4*)(Ws + (size_t)d * DD);
        float acc = 0.f;
        for (int j = 0; j < DD/4; ++j) {
            float4 w = wrow[j];
            acc += w.x*xs[j*4] + w.y*xs[j*4+1] + w.z*xs[j*4+2] + w.w*xs[j*4+3];
        }
        size_t idx = (size_t)b*DD + d;
        mnew[idx] = g * m[idx] + (1.f - g) * (mund[idx] + acc);
    }
}

extern "C" void kernel_launch(void* const* d_in, const int* in_sizes, int n_in,
                              void* d_out, int out_size, void* d_ws, size_t ws_size,
                              hipStream_t stream)
{
    (void)in_sizes; (void)n_in; (void)out_size; (void)ws_size;
    const float* c    = (const float*)d_in[0];
    const float* m    = (const float*)d_in[1];
    const float* k    = (const float*)d_in[2];
    const float* q    = (const float*)d_in[3];
    const float* cw   = (const float*)d_in[4];
    const int*   mask = (const int*)  d_in[5];
    const float* cs   = (const float*)d_in[6];
    const float* ms   = (const float*)d_in[7];
    const float* Wcq  = (const float*)d_in[8];
    const float* bcq  = (const float*)d_in[9];
    const float* Wca  = (const float*)d_in[10];
    const float* bca  = (const float*)d_in[11];
    const float* Wm_r = (const float*)d_in[12];
    const float* bm_r = (const float*)d_in[13];
    const float* Wk   = (const float*)d_in[14];
    const float* bk   = (const float*)d_in[15];
    const float* WI   = (const float*)d_in[16];
    const float* bI   = (const float*)d_in[17];
    const float* Wra  = (const float*)d_in[18];
    const float* bra  = (const float*)d_in[19];
    const float* Wm_w = (const float*)d_in[20];
    const float* bm_w = (const float*)d_in[21];
    const float* Wsa  = (const float*)d_in[22];
    const float* bsa  = (const float*)d_in[23];
    const float* Wm2  = (const float*)d_in[24];
    const float* bm2  = (const float*)d_in[25];
    const float* Wc   = (const float*)d_in[26];
    const float* bc   = (const float*)d_in[27];
    const float* Ws   = (const float*)d_in[28];

    float* out_cnew = (float*)d_out;
    float* out_mnew = out_cnew + BB*DD;
    float* out_cv   = out_mnew + BB*DD;
    float* out_rv   = out_cv + BB*LL;     // 25,690,112 f32 = 102,760,448 B

    // d_out rv region doubles as bf16 scratch for I / I2' (both dead before rv is written)
    unsigned short* I_w  = (unsigned short*)out_rv;                       // 51,380,224 B
    unsigned short* I2_w = (unsigned short*)((char*)out_rv + 51380224);   // 51,380,224 B

    char* w = (char*)d_ws;                 // total footprint: 55,575,552 B
    float* s0      = (float*)(w + 0);        // cq -> r
    float* s1      = (float*)(w + 524288);   // cnew
    float* s2      = (float*)(w + 1048576);  // mI -> mund
    float* s3      = (float*)(w + 1572864);  // mprev -> msa
    unsigned short* Wkb  = (unsigned short*)(w + 2097152);   // 512x512 bf16
    unsigned short* WIb  = (unsigned short*)(w + 2621440);   // 512x1024 bf16
    unsigned short* Wrab = (unsigned short*)(w + 3670016);   // 512x512 bf16
    unsigned short* ra_w = (unsigned short*)(w + 4194304);   // [B,D,HW] bf16, 51,380,224 B
    float* gate_w  = (float*)(w + 55574528); // 1024 B

    float* cq_w   = s0;
    float* r_w    = s0;
    float* cnew_w = s1;
    float* mI_w   = s2;
    float* mund_w = s2;
    float* mprev_w= s3;
    float* msa_w  = s3;

    // Weight converts (f32 -> bf16), L2-resident thereafter
    cvt_w_kernel<<<256, 256, 0, stream>>>(Wk,  Wkb,  65536);
    cvt_w_kernel<<<512, 256, 0, stream>>>(WI,  WIb,  131072);
    cvt_w_kernel<<<256, 256, 0, stream>>>(Wra, Wrab, 65536);

    // ControlUnit
    small_gemm_kernel<<<BB, 256, 0, stream>>>(c, DD, q, DD, Wcq, bcq, cq_w, DD);
    small_gemm_kernel<<<BB, 256, 0, stream>>>(m, DD, nullptr, 0, Wm_r, bm_r, mI_w, DD);
    control_kernel<<<BB, 256, 0, stream>>>(cq_w, cw, Wca, bca, mask, cnew_w, out_cv, out_cnew);

    // ReadUnit (MFMA convs): I = mI.(Wk k + bk); I2' = (WI [I;k] + bI).cnew; ra = Wra I2' + bra
    conv_mfma_kernel<<<dim3(BB, 4), 512, 0, stream>>>(k,    1, DD, nullptr, 0, Wkb,  DD,   bk,  mI_w,   I_w);
    conv_mfma_kernel<<<dim3(BB, 4), 512, 0, stream>>>(I_w,  0, DD, k,       1, WIb,  2*DD, bI,  cnew_w, I2_w);
    conv_mfma_kernel<<<dim3(BB, 4), 512, 0, stream>>>(I2_w, 0, DD, nullptr, 0, Wrab, DD,   bra, nullptr, ra_w);
    softmax_r_kernel<<<BB, 512, 0, stream>>>((const bf16*)ra_w, k, out_rv, r_w);

    // WriteUnit
    small_gemm_kernel<<<BB, 256, 0, stream>>>(r_w, DD, m, DD, Wm_w, bm_w, mprev_w, DD);
    small_gemm_kernel<<<BB, 256, 0, stream>>>(mprev_w, DD, nullptr, 0, Wm2, bm2, mund_w, DD);
    samsa_kernel<<<BB, 256, 0, stream>>>(cs, ms, Wsa, bsa, cnew_w, Wc, bc, gate_w, msa_w);
    write_final_kernel<<<BB, 256, 0, stream>>>(msa_w, Ws, m, gate_w, mund_w, out_mnew);
}